// Round 1
// baseline (602.817 us; speedup 1.0000x reference)
//
#include <hip/hip_runtime.h>

// Problem: B=8, N=196, C=512, NC=10, H=8, HD=64, SCALE=0.125
//
// Restructured dataflow (avoids materializing right_attn and attn):
//   xq  = x @ Wqk, xq2 = x @ Wqk2, xv = x @ Wv          (proj5)
//   aq  = anchors @ Wqk, aq2 = anchors @ Wqk2           (proj5)
//   rv[b,c,h]  = relu(+S*k2@q2^T) @ v[b,h]              (rv_kernel, fused)
//   left[b,c,h]= relu(-S*q@k^T)  -> written to d_out    (attn_out_kernel)
//   out1[b,h]  = sum_c w[b,h,c] * left[b,c,h] @ rv[b,c,h]  (same kernel)
//   out = flat(out1) @ Wproj + bproj                    (gemm512)
//
// ws layout (floats):
#define OFF_XQ   0          // 1568*512
#define OFF_XQ2  802816
#define OFF_XV   1605632
#define OFF_AQ   2408448    // 1960*512
#define OFF_AQ2  3411968
#define OFF_RV   4415488    // 640*196*64
#define OFF_OUT1 12443648   // 1568*512
// total = 13246464 floats = 52.99 MB

#define FMA16(s, a4, b4)                                    \
  { float a_[4] = {(a4).x, (a4).y, (a4).z, (a4).w};         \
    float b_[4] = {(b4).x, (b4).y, (b4).z, (b4).w};         \
    _Pragma("unroll") for (int i_ = 0; i_ < 4; i_++)        \
    _Pragma("unroll") for (int j_ = 0; j_ < 4; j_++)        \
      s[i_][j_] = fmaf(a_[i_], b_[j_], s[i_][j_]); }

// Load a 64-row x 64-col tile transposed into LDS: T[d][row]. Zero-pads rows >= nrows.
__device__ __forceinline__ void load_tile_T(float T[64][68], const float* __restrict__ g,
                                            int row0, int nrows, int stride, int col0, int tid) {
  int r = tid >> 2;            // 0..63
  int dq = (tid & 3) << 4;     // 0,16,32,48
  float4 v0, v1, v2, v3;
  if (r < nrows) {
    const float* p = g + (size_t)(row0 + r) * stride + col0 + dq;
    v0 = *(const float4*)(p);
    v1 = *(const float4*)(p + 4);
    v2 = *(const float4*)(p + 8);
    v3 = *(const float4*)(p + 12);
  } else {
    v0 = v1 = v2 = v3 = make_float4(0.f, 0.f, 0.f, 0.f);
  }
  T[dq + 0][r] = v0.x;  T[dq + 1][r] = v0.y;  T[dq + 2][r] = v0.z;  T[dq + 3][r] = v0.w;
  T[dq + 4][r] = v1.x;  T[dq + 5][r] = v1.y;  T[dq + 6][r] = v1.z;  T[dq + 7][r] = v1.w;
  T[dq + 8][r] = v2.x;  T[dq + 9][r] = v2.y;  T[dq +10][r] = v2.z;  T[dq +11][r] = v2.w;
  T[dq +12][r] = v3.x;  T[dq +13][r] = v3.y;  T[dq +14][r] = v3.z;  T[dq +15][r] = v3.w;
}

// Load a 64-row x 64-col tile row-major into LDS: T[row][col] (scaled). Zero-pads rows >= nrows.
__device__ __forceinline__ void load_tile_R(float T[64][68], const float* __restrict__ g,
                                            int row0, int nrows, int stride, int col0, int tid,
                                            float scale) {
  int r = tid >> 2;
  int dq = (tid & 3) << 4;
  float4 v0, v1, v2, v3;
  if (r < nrows) {
    const float* p = g + (size_t)(row0 + r) * stride + col0 + dq;
    v0 = *(const float4*)(p);
    v1 = *(const float4*)(p + 4);
    v2 = *(const float4*)(p + 8);
    v3 = *(const float4*)(p + 12);
    v0.x *= scale; v0.y *= scale; v0.z *= scale; v0.w *= scale;
    v1.x *= scale; v1.y *= scale; v1.z *= scale; v1.w *= scale;
    v2.x *= scale; v2.y *= scale; v2.z *= scale; v2.w *= scale;
    v3.x *= scale; v3.y *= scale; v3.z *= scale; v3.w *= scale;
  } else {
    v0 = v1 = v2 = v3 = make_float4(0.f, 0.f, 0.f, 0.f);
  }
  *(float4*)&T[r][dq + 0]  = v0;
  *(float4*)&T[r][dq + 4]  = v1;
  *(float4*)&T[r][dq + 8]  = v2;
  *(float4*)&T[r][dq + 12] = v3;
}

// ---------- generic 64x64-tile GEMM: out[M,512] = A[M,512] @ W[512,512] (+bias) ----------
__device__ __forceinline__ void gemm_body(const float* __restrict__ A, const float* __restrict__ W,
                                          const float* __restrict__ bias, float* __restrict__ out,
                                          int M, int row_blk, int col_blk) {
  __shared__ float At[16][68];   // [k][row]
  __shared__ float Ws[16][68];   // [k][col]
  int row0 = row_blk * 64;
  if (row0 >= M) return;         // uniform per block
  int col0 = col_blk * 64;
  int tid = threadIdx.x;
  int tx = tid & 15, ty = tid >> 4;
  int tx4 = tx << 2, ty4 = ty << 2;
  int ar = tid >> 2, ac = (tid & 3) << 2;     // A-tile loader: row, col4
  int wr = tid >> 4, wc = (tid & 15) << 2;    // W-tile loader
  float acc[4][4] = {};
  for (int k0 = 0; k0 < 512; k0 += 16) {
    float4 av;
    if (row0 + ar < M) av = *(const float4*)&A[(size_t)(row0 + ar) * 512 + k0 + ac];
    else               av = make_float4(0.f, 0.f, 0.f, 0.f);
    At[ac + 0][ar] = av.x; At[ac + 1][ar] = av.y; At[ac + 2][ar] = av.z; At[ac + 3][ar] = av.w;
    *(float4*)&Ws[wr][wc] = *(const float4*)&W[(size_t)(k0 + wr) * 512 + col0 + wc];
    __syncthreads();
#pragma unroll
    for (int kk = 0; kk < 16; kk++) {
      float4 a4 = *(float4*)&At[kk][ty4];
      float4 b4 = *(float4*)&Ws[kk][tx4];
      FMA16(acc, a4, b4);
    }
    __syncthreads();
  }
  float bv[4] = {0.f, 0.f, 0.f, 0.f};
  if (bias) {
    float4 b4 = *(const float4*)&bias[col0 + tx4];
    bv[0] = b4.x; bv[1] = b4.y; bv[2] = b4.z; bv[3] = b4.w;
  }
#pragma unroll
  for (int i = 0; i < 4; i++) {
    int r = row0 + ty4 + i;
    if (r < M) {
      float4 o = make_float4(acc[i][0] + bv[0], acc[i][1] + bv[1],
                             acc[i][2] + bv[2], acc[i][3] + bv[3]);
      *(float4*)&out[(size_t)r * 512 + col0 + tx4] = o;
    }
  }
}

__global__ __launch_bounds__(256) void proj5(const float* __restrict__ x, const float* __restrict__ anchors,
                                             const float* __restrict__ Wqk, const float* __restrict__ Wqk2,
                                             const float* __restrict__ Wv, float* __restrict__ ws) {
  const float* A; const float* W; float* O; int M;
  switch (blockIdx.z) {
    case 0:  A = x;       W = Wqk;  O = ws + OFF_XQ;  M = 1568; break;
    case 1:  A = x;       W = Wqk2; O = ws + OFF_XQ2; M = 1568; break;
    case 2:  A = x;       W = Wv;   O = ws + OFF_XV;  M = 1568; break;
    case 3:  A = anchors; W = Wqk;  O = ws + OFF_AQ;  M = 1960; break;
    default: A = anchors; W = Wqk2; O = ws + OFF_AQ2; M = 1960; break;
  }
  gemm_body(A, W, nullptr, O, M, blockIdx.x, blockIdx.y);
}

__global__ __launch_bounds__(256) void gemm512(const float* __restrict__ A, const float* __restrict__ W,
                                               const float* __restrict__ bias, float* __restrict__ out, int M) {
  gemm_body(A, W, bias, out, M, blockIdx.x, blockIdx.y);
}

// ---------- rv[b,c,h] = relu(0.125 * k2 @ q2^T) @ v[b,h] ----------
// grid: (4 i-tiles, 640 bch), block 256. Never materializes right_attn.
__global__ __launch_bounds__(256) void rv_kernel(const float* __restrict__ xq2, const float* __restrict__ aq2,
                                                 const float* __restrict__ xv, float* __restrict__ rv) {
  __shared__ float K2t[64][68];  // [d][i]  rows of right (anchor tokens)
  __shared__ float Bt[64][68];   // stage1: Q2t [d][j];  stage2: V [j][dd]
  __shared__ float Ss[64][65];   // S tile [i][j]
  int i0 = blockIdx.x << 6;
  int bch = blockIdx.y;                 // (b*10 + c)*8 + h
  int h = bch & 7;
  int bc = bch >> 3;
  int c = bc % 10;
  int b = bc / 10;
  int ni = min(64, 196 - i0);
  int tid = threadIdx.x;
  int tx4 = (tid & 15) << 2, ty4 = (tid >> 4) << 2;

  load_tile_T(K2t, aq2, c * 196 + i0, ni, 512, h * 64, tid);
  float acc[4][4] = {};
  for (int jt = 0; jt < 4; jt++) {
    int j0 = jt << 6;
    int nj = min(64, 196 - j0);
    __syncthreads();   // prev stage-2 done with Bt/Ss
    load_tile_T(Bt, xq2, b * 196 + j0, nj, 512, h * 64, tid);   // Q2t
    __syncthreads();   // K2t (first iter) + Q2t ready
    float s[4][4] = {};
#pragma unroll 8
    for (int d = 0; d < 64; d++) {
      float4 a4 = *(float4*)&K2t[d][ty4];
      float4 b4 = *(float4*)&Bt[d][tx4];
      FMA16(s, a4, b4);
    }
    __syncthreads();   // everyone done reading Q2t
#pragma unroll
    for (int ii = 0; ii < 4; ii++)
#pragma unroll
      for (int jj = 0; jj < 4; jj++)
        Ss[ty4 + ii][tx4 + jj] = fmaxf(0.125f * s[ii][jj], 0.f);
    load_tile_R(Bt, xv, b * 196 + j0, nj, 512, h * 64, tid, 1.f);  // V
    __syncthreads();   // Ss + V ready
#pragma unroll 4
    for (int j = 0; j < 64; j++) {
      float4 v4 = *(float4*)&Bt[j][tx4];
      float s0 = Ss[ty4 + 0][j], s1 = Ss[ty4 + 1][j];
      float s2 = Ss[ty4 + 2][j], s3 = Ss[ty4 + 3][j];
      acc[0][0] = fmaf(s0, v4.x, acc[0][0]); acc[0][1] = fmaf(s0, v4.y, acc[0][1]);
      acc[0][2] = fmaf(s0, v4.z, acc[0][2]); acc[0][3] = fmaf(s0, v4.w, acc[0][3]);
      acc[1][0] = fmaf(s1, v4.x, acc[1][0]); acc[1][1] = fmaf(s1, v4.y, acc[1][1]);
      acc[1][2] = fmaf(s1, v4.z, acc[1][2]); acc[1][3] = fmaf(s1, v4.w, acc[1][3]);
      acc[2][0] = fmaf(s2, v4.x, acc[2][0]); acc[2][1] = fmaf(s2, v4.y, acc[2][1]);
      acc[2][2] = fmaf(s2, v4.z, acc[2][2]); acc[2][3] = fmaf(s2, v4.w, acc[2][3]);
      acc[3][0] = fmaf(s3, v4.x, acc[3][0]); acc[3][1] = fmaf(s3, v4.y, acc[3][1]);
      acc[3][2] = fmaf(s3, v4.z, acc[3][2]); acc[3][3] = fmaf(s3, v4.w, acc[3][3]);
    }
  }
  size_t base = (size_t)bch * (196 * 64);
#pragma unroll
  for (int ii = 0; ii < 4; ii++) {
    int r = i0 + ty4 + ii;
    if (r < 196) {
      float4 o = make_float4(acc[ii][0], acc[ii][1], acc[ii][2], acc[ii][3]);
      *(float4*)&rv[base + (size_t)r * 64 + tx4] = o;
    }
  }
}

// ---------- left = relu(-0.125*q@k^T) -> d_out; out1[b,h] = sum_c w * left @ rv ----------
// grid: (4 i-tiles, 64 bh), block 256.
__global__ __launch_bounds__(256) void attn_out_kernel(const float* __restrict__ xq, const float* __restrict__ aq,
                                                       const float* __restrict__ rv, const float* __restrict__ weights,
                                                       float* __restrict__ left, float* __restrict__ out1) {
  __shared__ float Qt[64][68];   // [d][i], persistent
  __shared__ float Bt[64][68];   // stage1: Kt [d][j]; stage2: w*RV [j][dd]
  __shared__ float Ss[64][65];   // left tile [i][j] (unscaled)
  int i0 = blockIdx.x << 6;
  int bh = blockIdx.y;           // b*8 + h
  int h = bh & 7, b = bh >> 3;
  int ni = min(64, 196 - i0);
  int tid = threadIdx.x;
  int tx4 = (tid & 15) << 2, ty4 = (tid >> 4) << 2;

  load_tile_T(Qt, xq, b * 196 + i0, ni, 512, h * 64, tid);
  float acc[4][4] = {};
  for (int c = 0; c < 10; c++) {
    float w = weights[bh * 10 + c];
    size_t lbase  = (size_t)((b * 10 + c) * 8 + h) * (196 * 196);
    size_t rvbase = (size_t)((b * 10 + c) * 8 + h) * (196 * 64);
    for (int jt = 0; jt < 4; jt++) {
      int j0 = jt << 6;
      int nj = min(64, 196 - j0);
      __syncthreads();  // prev stage-2 done with Bt/Ss
      load_tile_T(Bt, aq, c * 196 + j0, nj, 512, h * 64, tid);   // Kt
      __syncthreads();
      float s[4][4] = {};
#pragma unroll 8
      for (int d = 0; d < 64; d++) {
        float4 a4 = *(float4*)&Qt[d][ty4];
        float4 b4 = *(float4*)&Bt[d][tx4];
        FMA16(s, a4, b4);
      }
      __syncthreads();  // everyone done reading Kt
#pragma unroll
      for (int ii = 0; ii < 4; ii++)
#pragma unroll
        for (int jj = 0; jj < 4; jj++)
          Ss[ty4 + ii][tx4 + jj] = fmaxf(-0.125f * s[ii][jj], 0.f);
      load_tile_R(Bt, rv + rvbase, j0, nj, 64, 0, tid, w);       // w * RV
      __syncthreads();  // Ss + RV ready
      // coalesced left_attn write from LDS
      {
        int col = tid & 63, rbase = tid >> 6;
        if (j0 + col < 196) {
#pragma unroll
          for (int u = 0; u < 16; u++) {
            int row = (u << 2) + rbase;
            if (i0 + row < 196)
              left[lbase + (size_t)(i0 + row) * 196 + (j0 + col)] = Ss[row][col];
          }
        }
      }
      // stage 2: acc += S @ (w*RV)
#pragma unroll 4
      for (int j = 0; j < 64; j++) {
        float4 v4 = *(float4*)&Bt[j][tx4];
        float s0 = Ss[ty4 + 0][j], s1 = Ss[ty4 + 1][j];
        float s2 = Ss[ty4 + 2][j], s3 = Ss[ty4 + 3][j];
        acc[0][0] = fmaf(s0, v4.x, acc[0][0]); acc[0][1] = fmaf(s0, v4.y, acc[0][1]);
        acc[0][2] = fmaf(s0, v4.z, acc[0][2]); acc[0][3] = fmaf(s0, v4.w, acc[0][3]);
        acc[1][0] = fmaf(s1, v4.x, acc[1][0]); acc[1][1] = fmaf(s1, v4.y, acc[1][1]);
        acc[1][2] = fmaf(s1, v4.z, acc[1][2]); acc[1][3] = fmaf(s1, v4.w, acc[1][3]);
        acc[2][0] = fmaf(s2, v4.x, acc[2][0]); acc[2][1] = fmaf(s2, v4.y, acc[2][1]);
        acc[2][2] = fmaf(s2, v4.z, acc[2][2]); acc[2][3] = fmaf(s2, v4.w, acc[2][3]);
        acc[3][0] = fmaf(s3, v4.x, acc[3][0]); acc[3][1] = fmaf(s3, v4.y, acc[3][1]);
        acc[3][2] = fmaf(s3, v4.z, acc[3][2]); acc[3][3] = fmaf(s3, v4.w, acc[3][3]);
      }
    }
  }
  // out1 layout (B,H,N,HD) flat == (1568, 512) rows for the final GEMM
#pragma unroll
  for (int ii = 0; ii < 4; ii++) {
    int r = i0 + ty4 + ii;
    if (r < 196) {
      float4 o = make_float4(acc[ii][0], acc[ii][1], acc[ii][2], acc[ii][3]);
      *(float4*)&out1[((size_t)bh * 196 + r) * 64 + tx4] = o;
    }
  }
}

extern "C" void kernel_launch(void* const* d_in, const int* in_sizes, int n_in,
                              void* d_out, int out_size, void* d_ws, size_t ws_size,
                              hipStream_t stream) {
  (void)in_sizes; (void)n_in; (void)out_size; (void)ws_size;
  const float* x       = (const float*)d_in[0];
  const float* anchors = (const float*)d_in[1];
  const float* weights = (const float*)d_in[2];
  const float* Wqk     = (const float*)d_in[3];
  const float* Wqk2    = (const float*)d_in[4];
  const float* Wv      = (const float*)d_in[5];
  const float* Wproj   = (const float*)d_in[6];
  const float* bproj   = (const float*)d_in[7];
  float* ws   = (float*)d_ws;    // needs 52,985,856 bytes
  float* out  = (float*)d_out;   // out: 802816 floats
  float* left = out + 802816;    // left_attn: 24,586,240 floats

  dim3 blk(256);
  proj5<<<dim3(31, 8, 5), blk, 0, stream>>>(x, anchors, Wqk, Wqk2, Wv, ws);
  rv_kernel<<<dim3(4, 640), blk, 0, stream>>>(ws + OFF_XQ2, ws + OFF_AQ2, ws + OFF_XV, ws + OFF_RV);
  attn_out_kernel<<<dim3(4, 64), blk, 0, stream>>>(ws + OFF_XQ, ws + OFF_AQ, ws + OFF_RV,
                                                   weights, left, ws + OFF_OUT1);
  gemm512<<<dim3(25, 8), blk, 0, stream>>>(ws + OFF_OUT1, Wproj, bproj, out, 1568);
}

// Round 2
// 242.716 us; speedup vs baseline: 2.4836x; 2.4836x over previous
//
#include <hip/hip_runtime.h>

// B=8, N=196, C=512, NC=10, H=8, HD=64, SCALE=0.125
//
// Dataflow (all matmuls on bf16 MFMA 16x16x32, fp32 accum):
//   proj5:   xq,xq2,xv (1568x512), aq,aq2 (1960x512)  -> bf16 in ws
//   rv:      rv_t[bch][dd][256] = (relu(+S*k2@q2^T) @ v)^T   bf16, j>=196 zeroed
//   attn:    left = relu(-S*q@k^T) -> d_out (fp32 from MFMA regs)
//            P[bh][c][n][dd] = left_c @ rv_c   bf16 partials  (grid split over c)
//   reduce:  out1[bh][n][dd] = sum_c w[bh,c] * P[...]         fp32
//   final:   out = out1 @ Wproj + bproj                       fp32
//
// ws layout (bytes):
#define OFF_XQ   0u          // 1568*512 bf16 = 1,605,632
#define OFF_XQ2  1605632u
#define OFF_XV   3211264u
#define OFF_AQ   4816896u    // 1960*512 bf16 = 2,007,040
#define OFF_AQ2  6823936u
#define OFF_RVT  8830976u    // 640*64*256 bf16 = 20,971,520
#define OFF_P    29802496u   // 640*196*64 bf16 = 16,056,320
#define OFF_OUT1 45858816u   // 1568*512 f32  = 3,211,264  -> end 49,070,080

typedef __attribute__((ext_vector_type(8))) short bf16x8;
typedef __attribute__((ext_vector_type(4))) float f32x4;
#define MFMA(a, b, c) __builtin_amdgcn_mfma_f32_16x16x32_bf16((a), (b), (c), 0, 0, 0)

__device__ __forceinline__ unsigned short f2bf(float x) {
  unsigned u = __builtin_bit_cast(unsigned, x);
  u += 0x7fffu + ((u >> 16) & 1u);          // round-to-nearest-even
  return (unsigned short)(u >> 16);
}
__device__ __forceinline__ float bf2f(unsigned short s) {
  return __builtin_bit_cast(float, ((unsigned)s) << 16);
}

// Load 64x64 bf16 tile row-major from [*, 512] global into T[row][col] (+8 pad). Zero rows >= nrows.
__device__ __forceinline__ void load_bf16_tile(unsigned short T[64][72], const unsigned short* __restrict__ g,
                                               int row0, int nrows, int col0, int tid) {
  int r = tid >> 2;
  int c0 = (tid & 3) << 4;
  uint4 a = make_uint4(0, 0, 0, 0), b = make_uint4(0, 0, 0, 0);
  if (r < nrows) {
    const unsigned short* p = g + (size_t)(row0 + r) * 512 + col0 + c0;
    a = *(const uint4*)p;
    b = *(const uint4*)(p + 8);
  }
  *(uint4*)&T[r][c0] = a;
  *(uint4*)&T[r][c0 + 8] = b;
}

// Load 64(rows=tokens j) x 64(cols=d) from [*, 512] global, TRANSPOSED into T[d][j]. Zero j >= nrows.
__device__ __forceinline__ void load_bf16_tile_T(unsigned short T[64][72], const unsigned short* __restrict__ g,
                                                 int row0, int nrows, int col0, int tid) {
#pragma unroll
  for (int rep = 0; rep < 2; rep++) {
    int j = (tid >> 3) + (rep << 5);
    int d0 = (tid & 7) << 3;
    uint4 a = make_uint4(0, 0, 0, 0);
    if (j < nrows) a = *(const uint4*)(g + (size_t)(row0 + j) * 512 + col0 + d0);
    unsigned short s[8];
    *(uint4*)s = a;
#pragma unroll
    for (int u = 0; u < 8; u++) T[d0 + u][j] = s[u];
  }
}

// ---- GEMM: out[M,512] = A[M,512](f32) @ W[512,512](f32), via bf16 MFMA ----
template <bool STORE_BF16>
__device__ __forceinline__ void gemm_mfma_body(const float* __restrict__ A, const float* __restrict__ W,
                                               const float* __restrict__ bias, void* __restrict__ outp,
                                               int M, int row_blk, int col_blk) {
  __shared__ unsigned short As[64][72];
  __shared__ unsigned short Wt[64][72];   // Wt[n][k]
  int row0 = row_blk << 6;
  if (row0 >= M) return;
  int col0 = col_blk << 6;
  int tid = threadIdx.x;
  int w = tid >> 6, lm = tid & 15, lq = (tid >> 4) & 3;
  f32x4 acc[4] = {};
  for (int k0 = 0; k0 < 512; k0 += 64) {
    {  // stage A rows (convert f32->bf16)
      int r = tid >> 2, c0 = (tid & 3) << 4;
      float4 f0, f1, f2, f3;
      if (row0 + r < M) {
        const float* p = A + (size_t)(row0 + r) * 512 + k0 + c0;
        f0 = *(const float4*)p;       f1 = *(const float4*)(p + 4);
        f2 = *(const float4*)(p + 8); f3 = *(const float4*)(p + 12);
      } else {
        f0 = f1 = f2 = f3 = make_float4(0.f, 0.f, 0.f, 0.f);
      }
      unsigned short s[16];
      s[0] = f2bf(f0.x);  s[1] = f2bf(f0.y);  s[2] = f2bf(f0.z);  s[3] = f2bf(f0.w);
      s[4] = f2bf(f1.x);  s[5] = f2bf(f1.y);  s[6] = f2bf(f1.z);  s[7] = f2bf(f1.w);
      s[8] = f2bf(f2.x);  s[9] = f2bf(f2.y);  s[10] = f2bf(f2.z); s[11] = f2bf(f2.w);
      s[12] = f2bf(f3.x); s[13] = f2bf(f3.y); s[14] = f2bf(f3.z); s[15] = f2bf(f3.w);
      *(uint4*)&As[r][c0] = *(uint4*)s;
      *(uint4*)&As[r][c0 + 8] = *(uint4*)(s + 8);
    }
#pragma unroll
    for (int rep = 0; rep < 2; rep++) {  // stage W transposed
      int k = (tid >> 3) + (rep << 5);
      int n0 = (tid & 7) << 3;
      const float* p = W + (size_t)(k0 + k) * 512 + col0 + n0;
      float4 g0 = *(const float4*)p, g1 = *(const float4*)(p + 4);
      Wt[n0 + 0][k] = f2bf(g0.x); Wt[n0 + 1][k] = f2bf(g0.y);
      Wt[n0 + 2][k] = f2bf(g0.z); Wt[n0 + 3][k] = f2bf(g0.w);
      Wt[n0 + 4][k] = f2bf(g1.x); Wt[n0 + 5][k] = f2bf(g1.y);
      Wt[n0 + 6][k] = f2bf(g1.z); Wt[n0 + 7][k] = f2bf(g1.w);
    }
    __syncthreads();
#pragma unroll
    for (int kk = 0; kk < 2; kk++) {
      bf16x8 bf = *(const bf16x8*)&Wt[(w << 4) + lm][(kk << 5) + (lq << 3)];
#pragma unroll
      for (int mi = 0; mi < 4; mi++) {
        bf16x8 af = *(const bf16x8*)&As[(mi << 4) + lm][(kk << 5) + (lq << 3)];
        acc[mi] = MFMA(af, bf, acc[mi]);
      }
    }
    __syncthreads();
  }
  int ncol = col0 + (w << 4) + lm;
  float bv = bias ? bias[ncol] : 0.f;
#pragma unroll
  for (int mi = 0; mi < 4; mi++)
#pragma unroll
    for (int r2 = 0; r2 < 4; r2++) {
      int row = row0 + (mi << 4) + (lq << 2) + r2;
      if (row < M) {
        if (STORE_BF16)
          ((unsigned short*)outp)[(size_t)row * 512 + ncol] = f2bf(acc[mi][r2]);
        else
          ((float*)outp)[(size_t)row * 512 + ncol] = acc[mi][r2] + bv;
      }
    }
}

__global__ __launch_bounds__(256) void proj5(const float* __restrict__ x, const float* __restrict__ anchors,
                                             const float* __restrict__ Wqk, const float* __restrict__ Wqk2,
                                             const float* __restrict__ Wv, char* __restrict__ ws) {
  const float* A; const float* W; unsigned short* O; int M;
  switch (blockIdx.z) {
    case 0:  A = x;       W = Wqk;  O = (unsigned short*)(ws + OFF_XQ);  M = 1568; break;
    case 1:  A = x;       W = Wqk2; O = (unsigned short*)(ws + OFF_XQ2); M = 1568; break;
    case 2:  A = x;       W = Wv;   O = (unsigned short*)(ws + OFF_XV);  M = 1568; break;
    case 3:  A = anchors; W = Wqk;  O = (unsigned short*)(ws + OFF_AQ);  M = 1960; break;
    default: A = anchors; W = Wqk2; O = (unsigned short*)(ws + OFF_AQ2); M = 1960; break;
  }
  gemm_mfma_body<true>(A, W, nullptr, O, M, blockIdx.x, blockIdx.y);
}

__global__ __launch_bounds__(256) void final_gemm(const float* __restrict__ A, const float* __restrict__ W,
                                                  const float* __restrict__ bias, float* __restrict__ out) {
  gemm_mfma_body<false>(A, W, bias, out, 1568, blockIdx.x, blockIdx.y);
}

// ---- rv_t[bch][dd][256] = (relu(0.125 * k2 @ q2^T) @ v)^T ----
__global__ __launch_bounds__(256) void rv_mfma(const unsigned short* __restrict__ xq2,
                                               const unsigned short* __restrict__ aq2,
                                               const unsigned short* __restrict__ xv,
                                               unsigned short* __restrict__ rvt) {
  __shared__ unsigned short Ks[64][72];  // anchors (i), persistent
  __shared__ unsigned short Qs[64][72];  // x-tokens (j), per jt
  __shared__ unsigned short Vt[64][72];  // Vt[dd][j]
  __shared__ unsigned short Ss[64][72];  // S bf16 [i][j]; reused for epilogue transpose
  int i0 = blockIdx.x << 6;
  int bch = blockIdx.y;
  int h = bch & 7, bc = bch >> 3;
  int c = bc % 10, b = bc / 10;
  int tid = threadIdx.x;
  int w = tid >> 6, lm = tid & 15, lq = (tid >> 4) & 3;
  int ni = min(64, 196 - i0);

  load_bf16_tile(Ks, aq2, c * 196 + i0, ni, h << 6, tid);
  __syncthreads();
  bf16x8 kf[4][2];
#pragma unroll
  for (int mi = 0; mi < 4; mi++)
#pragma unroll
    for (int kk = 0; kk < 2; kk++)
      kf[mi][kk] = *(const bf16x8*)&Ks[(mi << 4) + lm][(kk << 5) + (lq << 3)];

  f32x4 acc[4] = {};
  for (int jt = 0; jt < 4; jt++) {
    int j0 = jt << 6;
    int nj = min(64, 196 - j0);
    __syncthreads();
    load_bf16_tile(Qs, xq2, b * 196 + j0, nj, h << 6, tid);
    load_bf16_tile_T(Vt, xv, b * 196 + j0, nj, h << 6, tid);
    __syncthreads();
    f32x4 s[4] = {};
#pragma unroll
    for (int kk = 0; kk < 2; kk++) {
      bf16x8 bf = *(const bf16x8*)&Qs[(w << 4) + lm][(kk << 5) + (lq << 3)];
#pragma unroll
      for (int mi = 0; mi < 4; mi++) s[mi] = MFMA(kf[mi][kk], bf, s[mi]);
    }
#pragma unroll
    for (int mi = 0; mi < 4; mi++)
#pragma unroll
      for (int r = 0; r < 4; r++)
        Ss[(mi << 4) + (lq << 2) + r][(w << 4) + lm] = f2bf(fmaxf(0.125f * s[mi][r], 0.f));
    __syncthreads();
#pragma unroll
    for (int kk = 0; kk < 2; kk++) {
      bf16x8 bf = *(const bf16x8*)&Vt[(w << 4) + lm][(kk << 5) + (lq << 3)];
#pragma unroll
      for (int mi = 0; mi < 4; mi++) {
        bf16x8 af = *(const bf16x8*)&Ss[(mi << 4) + lm][(kk << 5) + (lq << 3)];
        acc[mi] = MFMA(af, bf, acc[mi]);
      }
    }
  }
  __syncthreads();
#pragma unroll
  for (int mi = 0; mi < 4; mi++)   // Ss[dd][i_loc] transpose
#pragma unroll
    for (int r = 0; r < 4; r++)
      Ss[(w << 4) + lm][(mi << 4) + (lq << 2) + r] = f2bf(acc[mi][r]);
  __syncthreads();
  {
    int dd = tid >> 2, seg = (tid & 3) << 4;
    unsigned short* dst = rvt + ((size_t)bch * 64 + dd) * 256 + i0 + seg;
    *(uint4*)dst = *(uint4*)&Ss[dd][seg];
    *(uint4*)(dst + 8) = *(uint4*)&Ss[dd][seg + 8];
  }
}

// ---- left = relu(-0.125*q@k^T) -> d_out;  P[bh][c][n][dd] = left @ rv (bf16) ----
__global__ __launch_bounds__(256) void attn_mfma(const unsigned short* __restrict__ xq,
                                                 const unsigned short* __restrict__ aq,
                                                 const unsigned short* __restrict__ rvt,
                                                 float* __restrict__ left,
                                                 unsigned short* __restrict__ P) {
  __shared__ unsigned short Qs[64][72];  // x-tokens (i), persistent
  __shared__ unsigned short Ks[64][72];  // anchors (j), per jt
  __shared__ unsigned short Rt[64][72];  // Rt[dd][j]
  __shared__ unsigned short Ss[64][72];
  int i0 = blockIdx.x << 6;
  int bh = blockIdx.y;
  int c = blockIdx.z;
  int b = bh >> 3, h = bh & 7;
  int bch = (b * 10 + c) * 8 + h;
  int tid = threadIdx.x;
  int w = tid >> 6, lm = tid & 15, lq = (tid >> 4) & 3;
  int ni = min(64, 196 - i0);

  load_bf16_tile(Qs, xq, b * 196 + i0, ni, h << 6, tid);
  __syncthreads();
  bf16x8 qf[4][2];
#pragma unroll
  for (int mi = 0; mi < 4; mi++)
#pragma unroll
    for (int kk = 0; kk < 2; kk++)
      qf[mi][kk] = *(const bf16x8*)&Qs[(mi << 4) + lm][(kk << 5) + (lq << 3)];

  f32x4 acc[4] = {};
  size_t lbase = (size_t)bch * (196 * 196);
  for (int jt = 0; jt < 4; jt++) {
    int j0 = jt << 6;
    int nj = min(64, 196 - j0);
    __syncthreads();
    load_bf16_tile(Ks, aq, c * 196 + j0, nj, h << 6, tid);
    {  // Rt rows straight from transposed rv_t (zero-padded past 196)
      int dd = tid >> 2, seg = (tid & 3) << 4;
      const unsigned short* src = rvt + ((size_t)bch * 64 + dd) * 256 + j0 + seg;
      *(uint4*)&Rt[dd][seg] = *(const uint4*)src;
      *(uint4*)&Rt[dd][seg + 8] = *(const uint4*)(src + 8);
    }
    __syncthreads();
    f32x4 s[4] = {};
#pragma unroll
    for (int kk = 0; kk < 2; kk++) {
      bf16x8 bf = *(const bf16x8*)&Ks[(w << 4) + lm][(kk << 5) + (lq << 3)];
#pragma unroll
      for (int mi = 0; mi < 4; mi++) s[mi] = MFMA(qf[mi][kk], bf, s[mi]);
    }
#pragma unroll
    for (int mi = 0; mi < 4; mi++)
#pragma unroll
      for (int r = 0; r < 4; r++) {
        float v = fmaxf(-0.125f * s[mi][r], 0.f);
        int il = (mi << 4) + (lq << 2) + r;
        int jl = (w << 4) + lm;
        Ss[il][jl] = f2bf(v);
        if (i0 + il < 196 && j0 + jl < 196)
          left[lbase + (size_t)(i0 + il) * 196 + (j0 + jl)] = v;  // exact fp32 from MFMA
      }
    __syncthreads();
#pragma unroll
    for (int kk = 0; kk < 2; kk++) {
      bf16x8 bf = *(const bf16x8*)&Rt[(w << 4) + lm][(kk << 5) + (lq << 3)];
#pragma unroll
      for (int mi = 0; mi < 4; mi++) {
        bf16x8 af = *(const bf16x8*)&Ss[(mi << 4) + lm][(kk << 5) + (lq << 3)];
        acc[mi] = MFMA(af, bf, acc[mi]);
      }
    }
  }
  __syncthreads();
#pragma unroll
  for (int mi = 0; mi < 4; mi++)   // Ss[i_loc][dd]
#pragma unroll
    for (int r = 0; r < 4; r++)
      Ss[(mi << 4) + (lq << 2) + r][(w << 4) + lm] = f2bf(acc[mi][r]);
  __syncthreads();
  {
    int row = tid >> 2, seg = (tid & 3) << 4;
    if (i0 + row < 196) {
      unsigned short* dst = P + ((size_t)(bh * 10 + c) * 196 + i0 + row) * 64 + seg;
      *(uint4*)dst = *(uint4*)&Ss[row][seg];
      *(uint4*)(dst + 8) = *(uint4*)&Ss[row][seg + 8];
    }
  }
}

// ---- out1[bh][n][dd] = sum_c weights[bh,c] * P[bh][c][n][dd] ----
__global__ __launch_bounds__(256) void reduce_out1(const unsigned short* __restrict__ P,
                                                   const float* __restrict__ weights,
                                                   float* __restrict__ out1) {
  int t = blockIdx.x * 256 + threadIdx.x;   // 200704 threads, 4 elems each
  int base = t << 2;
  int bh = base / 12544;
  int rem = base - bh * 12544;
  const float* wrow = weights + bh * 10;
  float a0 = 0.f, a1 = 0.f, a2 = 0.f, a3 = 0.f;
#pragma unroll
  for (int c = 0; c < 10; c++) {
    float wc = wrow[c];
    const unsigned short* p = P + ((size_t)(bh * 10 + c)) * 12544 + rem;
    ushort4 u = *(const ushort4*)p;
    a0 = fmaf(wc, bf2f(u.x), a0);
    a1 = fmaf(wc, bf2f(u.y), a1);
    a2 = fmaf(wc, bf2f(u.z), a2);
    a3 = fmaf(wc, bf2f(u.w), a3);
  }
  *(float4*)&out1[base] = make_float4(a0, a1, a2, a3);
}

extern "C" void kernel_launch(void* const* d_in, const int* in_sizes, int n_in,
                              void* d_out, int out_size, void* d_ws, size_t ws_size,
                              hipStream_t stream) {
  (void)in_sizes; (void)n_in; (void)out_size; (void)ws_size;
  const float* x       = (const float*)d_in[0];
  const float* anchors = (const float*)d_in[1];
  const float* weights = (const float*)d_in[2];
  const float* Wqk     = (const float*)d_in[3];
  const float* Wqk2    = (const float*)d_in[4];
  const float* Wv      = (const float*)d_in[5];
  const float* Wproj   = (const float*)d_in[6];
  const float* bproj   = (const float*)d_in[7];
  char* ws = (char*)d_ws;                     // needs 49,070,080 bytes (< 53MB proven)
  float* out  = (float*)d_out;                // 802,816 floats
  float* left = out + 802816;                 // left_attn 24,586,240 floats

  unsigned short* xq  = (unsigned short*)(ws + OFF_XQ);
  unsigned short* xq2 = (unsigned short*)(ws + OFF_XQ2);
  unsigned short* xv  = (unsigned short*)(ws + OFF_XV);
  unsigned short* aq  = (unsigned short*)(ws + OFF_AQ);
  unsigned short* aq2 = (unsigned short*)(ws + OFF_AQ2);
  unsigned short* rvt = (unsigned short*)(ws + OFF_RVT);
  unsigned short* P   = (unsigned short*)(ws + OFF_P);
  float* out1         = (float*)(ws + OFF_OUT1);

  dim3 blk(256);
  proj5<<<dim3(31, 8, 5), blk, 0, stream>>>(x, anchors, Wqk, Wqk2, Wv, ws);
  rv_mfma<<<dim3(4, 640), blk, 0, stream>>>(xq2, aq2, xv, rvt);
  attn_mfma<<<dim3(4, 64, 10), blk, 0, stream>>>(xq, aq, rvt, left, P);
  reduce_out1<<<dim3(784), blk, 0, stream>>>(P, weights, out1);
  final_gemm<<<dim3(25, 8), blk, 0, stream>>>(out1, Wproj, bproj, out);
}

// Round 3
// 230.407 us; speedup vs baseline: 2.6163x; 1.0534x over previous
//
#include <hip/hip_runtime.h>

// B=8, N=196, C=512, NC=10, H=8, HD=64, SCALE=0.125
//
// Pipeline (all matmuls bf16 MFMA 16x16x32, fp32 accum):
//   pre:     x,anchors -> bf16;  Wqk,Wqk2,Wv,Wproj -> bf16 TRANSPOSED [n][k]
//   proj5:   xq,xq2,xv (1568x512), aq,aq2 (1960x512) bf16, pure-bf16 GEMM
//   rv:      rvt[bch][it][64dd][64j] = (relu(+S*k2@q2^T) @ v)^T  (jt-blocked, pads zeroed)
//   attn:    left = relu(-S*q@k^T) -> d_out (fp32); P[bh][c][n][dd] bf16
//   reduce:  out1 = sum_c w * P   (bf16)
//   final:   out = out1 @ Wproj + bproj (f32)
// Hot staging uses __builtin_amdgcn_global_load_lds width=16 into [64][72] LDS.
//
// ws layout (bytes), total 53,174,272 (<= 52,985,856+pad proven OK in R1... 50.7MB):
#define OFF_XB     0u          // x bf16        1,605,632
#define OFF_AB     1605632u    // anchors bf16  2,007,040
#define OFF_WQKT   3612672u    // 512x512 bf16 T  524,288
#define OFF_WQK2T  4136960u
#define OFF_WVT    4661248u
#define OFF_WPROJT 5185536u
#define OFF_XQ     5709824u    // 1,605,632
#define OFF_XQ2    7315456u
#define OFF_XV     8921088u
#define OFF_AQ     10526720u   // 2,007,040
#define OFF_AQ2    12533760u
#define OFF_RVT    14540800u   // 640*4*64*64*2 = 20,971,520
#define OFF_OUT1   35512320u   // 1568*512 bf16 = 1,605,632
#define OFF_P      37117952u   // 640*196*64 bf16 = 16,056,320 -> end 53,174,272

typedef __attribute__((ext_vector_type(8))) short bf16x8;
typedef __attribute__((ext_vector_type(4))) float f32x4;
#define MFMA(a, b, c) __builtin_amdgcn_mfma_f32_16x16x32_bf16((a), (b), (c), 0, 0, 0)

__device__ __forceinline__ unsigned short f2bf(float x) {
  unsigned u = __builtin_bit_cast(unsigned, x);
  u += 0x7fffu + ((u >> 16) & 1u);
  return (unsigned short)(u >> 16);
}
__device__ __forceinline__ float bf2f(unsigned short s) {
  return __builtin_bit_cast(float, ((unsigned)s) << 16);
}

__device__ __forceinline__ void gl_lds16(const void* g, void* l) {
  __builtin_amdgcn_global_load_lds(
      (const __attribute__((address_space(1))) unsigned int*)g,
      (__attribute__((address_space(3))) unsigned int*)l, 16, 0, 0);
}

// Stage a 64x64 bf16 tile (row stride `stride` shorts) into LDS [64][72] via
// global_load_lds. LDS row = 144B = 9 chunks of 16B; chunk 8 of each row loads
// 16B of garbage (source cols 64..71) into the pad - never read as data.
// Rows >= nrows are skipped (caller pre-zeroes LDS if zeros required).
__device__ __forceinline__ void stage64(const unsigned short* g0, int stride,
                                        unsigned short (*T)[72], int tid, int nrows) {
  int wv = tid >> 6;
  char* base = (char*)&T[0][0];
#pragma unroll
  for (int i = 0; i < 2; i++) {
    int k = i * 256 + tid;
    int r = k / 9, c = k - r * 9;
    if (r < nrows)
      gl_lds16(g0 + (size_t)r * stride + (c << 3), base + (((i << 2) + wv) << 10));
  }
  if (tid < 64) {
    int k = 512 + tid;
    int r = k / 9, c = k - r * 9;
    if (r < nrows)
      gl_lds16(g0 + (size_t)r * stride + (c << 3), base + 8192);
  }
}

// Plain VGPR-roundtrip tile load with zero padding for rows >= nrows.
__device__ __forceinline__ void load_bf16_tile(unsigned short T[64][72], const unsigned short* __restrict__ g,
                                               int row0, int nrows, int col0, int tid) {
  int r = tid >> 2;
  int c0 = (tid & 3) << 4;
  uint4 a = make_uint4(0, 0, 0, 0), b = make_uint4(0, 0, 0, 0);
  if (r < nrows) {
    const unsigned short* p = g + (size_t)(row0 + r) * 512 + col0 + c0;
    a = *(const uint4*)p;
    b = *(const uint4*)(p + 8);
  }
  *(uint4*)&T[r][c0] = a;
  *(uint4*)&T[r][c0 + 8] = b;
}

// Transposed tile load (for V): T[d][j], zero for j >= nrows.
__device__ __forceinline__ void load_bf16_tile_T(unsigned short T[64][72], const unsigned short* __restrict__ g,
                                                 int row0, int nrows, int col0, int tid) {
#pragma unroll
  for (int rep = 0; rep < 2; rep++) {
    int j = (tid >> 3) + (rep << 5);
    int d0 = (tid & 7) << 3;
    uint4 a = make_uint4(0, 0, 0, 0);
    if (j < nrows) a = *(const uint4*)(g + (size_t)(row0 + j) * 512 + col0 + d0);
    unsigned short s[8];
    *(uint4*)s = a;
#pragma unroll
    for (int u = 0; u < 8; u++) T[d0 + u][j] = s[u];
  }
}

// ---- pre: bf16 conversions + W transposes ----
__global__ __launch_bounds__(256) void pre_kernel(const float* __restrict__ x, const float* __restrict__ anchors,
                                                  const float* __restrict__ Wqk, const float* __restrict__ Wqk2,
                                                  const float* __restrict__ Wv, const float* __restrict__ Wproj,
                                                  char* __restrict__ ws) {
  int tid = threadIdx.x;
  if (blockIdx.x < 1764) {  // flat convert x (802816) + anchors (1003520) -> XB/AB (contiguous)
    int base = blockIdx.x * 1024 + (tid << 2);
    float4 f = (base < 802816) ? *(const float4*)(x + base)
                               : *(const float4*)(anchors + (base - 802816));
    unsigned short s[4] = {f2bf(f.x), f2bf(f.y), f2bf(f.z), f2bf(f.w)};
    *(uint2*)((unsigned short*)(ws + OFF_XB) + base) = *(uint2*)s;
    return;
  }
  // W transpose tiles: 4 matrices x 64 tiles
  __shared__ unsigned short Ls[64][72];
  int idx = blockIdx.x - 1764;
  int wsel = idx >> 6, t = idx & 63;
  int k0 = (t >> 3) << 6, n0 = (t & 7) << 6;
  const float* W;
  unsigned short* WT;
  switch (wsel) {
    case 0:  W = Wqk;   WT = (unsigned short*)(ws + OFF_WQKT);   break;
    case 1:  W = Wqk2;  WT = (unsigned short*)(ws + OFF_WQK2T);  break;
    case 2:  W = Wv;    WT = (unsigned short*)(ws + OFF_WVT);    break;
    default: W = Wproj; WT = (unsigned short*)(ws + OFF_WPROJT); break;
  }
  {  // load [k][n] tile, convert
    int r = tid >> 2, seg = (tid & 3) << 4;
    const float* p = W + (size_t)(k0 + r) * 512 + n0 + seg;
    float4 f0 = *(const float4*)p, f1 = *(const float4*)(p + 4);
    float4 f2 = *(const float4*)(p + 8), f3 = *(const float4*)(p + 12);
    unsigned short s[16] = {f2bf(f0.x), f2bf(f0.y), f2bf(f0.z), f2bf(f0.w),
                            f2bf(f1.x), f2bf(f1.y), f2bf(f1.z), f2bf(f1.w),
                            f2bf(f2.x), f2bf(f2.y), f2bf(f2.z), f2bf(f2.w),
                            f2bf(f3.x), f2bf(f3.y), f2bf(f3.z), f2bf(f3.w)};
    *(uint4*)&Ls[r][seg] = *(uint4*)s;
    *(uint4*)&Ls[r][seg + 8] = *(uint4*)(s + 8);
  }
  __syncthreads();
  {  // write transposed rows [n][k]
    int r = tid >> 2, seg = (tid & 3) << 4;
    unsigned short s[16];
#pragma unroll
    for (int u = 0; u < 16; u++) s[u] = Ls[seg + u][r];
    unsigned short* dst = WT + (size_t)(n0 + r) * 512 + k0 + seg;
    *(uint4*)dst = *(uint4*)s;
    *(uint4*)(dst + 8) = *(uint4*)(s + 8);
  }
}

// ---- pure-bf16 GEMM: out[M,512] = A[M,512] @ WT^T (+bias) ----
template <bool STORE_BF16>
__device__ __forceinline__ void gemm_bf16_body(const unsigned short* __restrict__ A,
                                               const unsigned short* __restrict__ WT,
                                               const float* __restrict__ bias, void* __restrict__ outp,
                                               int M, int row_blk, int col_blk) {
  __shared__ unsigned short As[64][72];
  __shared__ unsigned short Ws[64][72];   // Ws[n][k]
  int row0 = row_blk << 6;
  if (row0 >= M) return;
  int col0 = col_blk << 6;
  int tid = threadIdx.x;
  int w = tid >> 6, lm = tid & 15, lq = (tid >> 4) & 3;
  f32x4 acc[4] = {};
  for (int k0 = 0; k0 < 512; k0 += 64) {
    __syncthreads();
    stage64(A + (size_t)row0 * 512 + k0, 512, As, tid, 64);   // garbage rows past M masked at store
    stage64(WT + (size_t)col0 * 512 + k0, 512, Ws, tid, 64);
    __syncthreads();
#pragma unroll
    for (int kk = 0; kk < 2; kk++) {
      bf16x8 bf = *(const bf16x8*)&Ws[(w << 4) + lm][(kk << 5) + (lq << 3)];
#pragma unroll
      for (int mi = 0; mi < 4; mi++) {
        bf16x8 af = *(const bf16x8*)&As[(mi << 4) + lm][(kk << 5) + (lq << 3)];
        acc[mi] = MFMA(af, bf, acc[mi]);
      }
    }
  }
  int ncol = col0 + (w << 4) + lm;
  float bv = bias ? bias[ncol] : 0.f;
#pragma unroll
  for (int mi = 0; mi < 4; mi++)
#pragma unroll
    for (int r2 = 0; r2 < 4; r2++) {
      int row = row0 + (mi << 4) + (lq << 2) + r2;
      if (row < M) {
        if (STORE_BF16)
          ((unsigned short*)outp)[(size_t)row * 512 + ncol] = f2bf(acc[mi][r2]);
        else
          ((float*)outp)[(size_t)row * 512 + ncol] = acc[mi][r2] + bv;
      }
    }
}

__global__ __launch_bounds__(256) void proj5(char* __restrict__ ws) {
  const unsigned short* xb = (const unsigned short*)(ws + OFF_XB);
  const unsigned short* ab = (const unsigned short*)(ws + OFF_AB);
  const unsigned short* A; const unsigned short* WT; unsigned short* O; int M;
  switch (blockIdx.z) {
    case 0:  A = xb; WT = (unsigned short*)(ws + OFF_WQKT);  O = (unsigned short*)(ws + OFF_XQ);  M = 1568; break;
    case 1:  A = xb; WT = (unsigned short*)(ws + OFF_WQK2T); O = (unsigned short*)(ws + OFF_XQ2); M = 1568; break;
    case 2:  A = xb; WT = (unsigned short*)(ws + OFF_WVT);   O = (unsigned short*)(ws + OFF_XV);  M = 1568; break;
    case 3:  A = ab; WT = (unsigned short*)(ws + OFF_WQKT);  O = (unsigned short*)(ws + OFF_AQ);  M = 1960; break;
    default: A = ab; WT = (unsigned short*)(ws + OFF_WQK2T); O = (unsigned short*)(ws + OFF_AQ2); M = 1960; break;
  }
  gemm_bf16_body<true>(A, WT, nullptr, O, M, blockIdx.x, blockIdx.y);
}

__global__ __launch_bounds__(256) void final_gemm(const unsigned short* __restrict__ out1,
                                                  const unsigned short* __restrict__ WT,
                                                  const float* __restrict__ bias, float* __restrict__ out) {
  gemm_bf16_body<false>(out1, WT, bias, out, 1568, blockIdx.x, blockIdx.y);
}

// ---- rv: rvt[bch][it][dd][j=64] = (relu(0.125 * k2 @ q2^T) @ v)^T, blocked by i-tile ----
__global__ __launch_bounds__(256) void rv_mfma(char* __restrict__ ws) {
  const unsigned short* xq2 = (const unsigned short*)(ws + OFF_XQ2);
  const unsigned short* aq2 = (const unsigned short*)(ws + OFF_AQ2);
  const unsigned short* xv  = (const unsigned short*)(ws + OFF_XV);
  unsigned short* rvt       = (unsigned short*)(ws + OFF_RVT);
  __shared__ unsigned short Ks[64][72];  // anchors (i), persistent, zero-padded
  __shared__ unsigned short Qs[64][72];  // x (j)
  __shared__ unsigned short Vt[64][72];  // Vt[dd][j], zero-padded
  __shared__ unsigned short Ss[64][72];
  int i0 = blockIdx.x << 6;
  int bch = blockIdx.y;
  int h = bch & 7, bc = bch >> 3;
  int c = bc % 10, b = bc / 10;
  int tid = threadIdx.x;
  int w = tid >> 6, lm = tid & 15, lq = (tid >> 4) & 3;
  int ni = min(64, 196 - i0);

  load_bf16_tile(Ks, aq2, c * 196 + i0, ni, h << 6, tid);
  __syncthreads();
  bf16x8 kf[4][2];
#pragma unroll
  for (int mi = 0; mi < 4; mi++)
#pragma unroll
    for (int kk = 0; kk < 2; kk++)
      kf[mi][kk] = *(const bf16x8*)&Ks[(mi << 4) + lm][(kk << 5) + (lq << 3)];

  f32x4 acc[4] = {};
  for (int jt = 0; jt < 4; jt++) {
    int j0 = jt << 6;
    int nj = min(64, 196 - j0);
    __syncthreads();
    stage64(xq2 + (size_t)(b * 196 + j0) * 512 + (h << 6), 512, Qs, tid, 64);  // garbage rows ok (Vt=0)
    load_bf16_tile_T(Vt, xv, b * 196 + j0, nj, h << 6, tid);
    __syncthreads();
    f32x4 s[4] = {};
#pragma unroll
    for (int kk = 0; kk < 2; kk++) {
      bf16x8 bf = *(const bf16x8*)&Qs[(w << 4) + lm][(kk << 5) + (lq << 3)];
#pragma unroll
      for (int mi = 0; mi < 4; mi++) s[mi] = MFMA(kf[mi][kk], bf, s[mi]);
    }
#pragma unroll
    for (int mi = 0; mi < 4; mi++)
#pragma unroll
      for (int r = 0; r < 4; r++)
        Ss[(mi << 4) + (lq << 2) + r][(w << 4) + lm] = f2bf(fmaxf(0.125f * s[mi][r], 0.f));
    __syncthreads();
#pragma unroll
    for (int kk = 0; kk < 2; kk++) {
      bf16x8 bf = *(const bf16x8*)&Vt[(w << 4) + lm][(kk << 5) + (lq << 3)];
#pragma unroll
      for (int mi = 0; mi < 4; mi++) {
        bf16x8 af = *(const bf16x8*)&Ss[(mi << 4) + lm][(kk << 5) + (lq << 3)];
        acc[mi] = MFMA(af, bf, acc[mi]);
      }
    }
  }
  __syncthreads();
#pragma unroll
  for (int mi = 0; mi < 4; mi++)   // transpose: Ss[dd][i_local]
#pragma unroll
    for (int r = 0; r < 4; r++)
      Ss[(w << 4) + lm][(mi << 4) + (lq << 2) + r] = f2bf(acc[mi][r]);
  __syncthreads();
  {  // rvt block [bch*4+it][dd][64] unpadded, rows i>=196 are zeros (Ks zero-padded)
    int dd = tid >> 2, seg = (tid & 3) << 4;
    unsigned short* dst = rvt + ((size_t)(bch * 4 + blockIdx.x) * 64 + dd) * 64 + seg;
    *(uint4*)dst = *(uint4*)&Ss[dd][seg];
    *(uint4*)(dst + 8) = *(uint4*)&Ss[dd][seg + 8];
  }
}

// ---- attn: left = relu(-0.125*q@k^T) -> d_out;  P[bh][c][n][dd] = left @ rv (bf16) ----
__global__ __launch_bounds__(256) void attn_mfma(char* __restrict__ ws, float* __restrict__ left,
                                                 unsigned short* __restrict__ P) {
  const unsigned short* xq  = (const unsigned short*)(ws + OFF_XQ);
  const unsigned short* aq  = (const unsigned short*)(ws + OFF_AQ);
  const unsigned short* rvt = (const unsigned short*)(ws + OFF_RVT);
  __shared__ unsigned short Qs[64][72];  // x (i), persistent (garbage rows ok)
  __shared__ unsigned short Ks[64][72];  // anchors (j), needs zero pad rows
  __shared__ unsigned short Rt[64][72];  // Rt[dd][j] (pads are zeros from rv)
  __shared__ unsigned short Ss[64][72];
  int i0 = blockIdx.x << 6;
  int bh = blockIdx.y;
  int c = blockIdx.z;
  int b = bh >> 3, h = bh & 7;
  int bch = (b * 10 + c) * 8 + h;
  int tid = threadIdx.x;
  int w = tid >> 6, lm = tid & 15, lq = (tid >> 4) & 3;

  stage64(xq + (size_t)(b * 196 + i0) * 512 + (h << 6), 512, Qs, tid, 64);
  bf16x8 qf[4][2];
  f32x4 acc[4] = {};
  size_t lbase = (size_t)bch * (196 * 196);
  // jt order {3,0,1,2}: jt=3's short tile is staged lane-masked against
  // pre-zeroed LDS rows; later jt's fully overwrite.
#pragma unroll
  for (int t = 0; t < 4; t++) {
    int jt = (t == 0) ? 3 : t - 1;
    int j0 = jt << 6;
    int nj = (jt == 3) ? 4 : 64;
    __syncthreads();  // t=0: drains Qs DMA; t>0: prev stage2 done with Ks/Rt/Ss
    if (t == 0) {     // zero Ks rows 4..63 once (8640B)
      uint4 z = make_uint4(0, 0, 0, 0);
      for (int k = tid; k < 540; k += 256)
        *(uint4*)((char*)&Ks[0][0] + 576 + k * 16) = z;
    }
    stage64(aq + (size_t)(c * 196 + j0) * 512 + (h << 6), 512, Ks, tid, nj);
    stage64(rvt + (size_t)(bch * 4 + jt) * 4096, 64, Rt, tid, 64);
    __syncthreads();
    if (t == 0) {
#pragma unroll
      for (int mi = 0; mi < 4; mi++)
#pragma unroll
        for (int kk = 0; kk < 2; kk++)
          qf[mi][kk] = *(const bf16x8*)&Qs[(mi << 4) + lm][(kk << 5) + (lq << 3)];
    }
    f32x4 s[4] = {};
#pragma unroll
    for (int kk = 0; kk < 2; kk++) {
      bf16x8 bf = *(const bf16x8*)&Ks[(w << 4) + lm][(kk << 5) + (lq << 3)];
#pragma unroll
      for (int mi = 0; mi < 4; mi++) s[mi] = MFMA(qf[mi][kk], bf, s[mi]);
    }
#pragma unroll
    for (int mi = 0; mi < 4; mi++)
#pragma unroll
      for (int r = 0; r < 4; r++) {
        float v = fmaxf(-0.125f * s[mi][r], 0.f);
        int il = (mi << 4) + (lq << 2) + r;
        int jl = (w << 4) + lm;
        Ss[il][jl] = f2bf(v);
        if (i0 + il < 196 && j0 + jl < 196)
          left[lbase + (size_t)(i0 + il) * 196 + (j0 + jl)] = v;
      }
    __syncthreads();
#pragma unroll
    for (int kk = 0; kk < 2; kk++) {
      bf16x8 bf = *(const bf16x8*)&Rt[(w << 4) + lm][(kk << 5) + (lq << 3)];
#pragma unroll
      for (int mi = 0; mi < 4; mi++) {
        bf16x8 af = *(const bf16x8*)&Ss[(mi << 4) + lm][(kk << 5) + (lq << 3)];
        acc[mi] = MFMA(af, bf, acc[mi]);
      }
    }
  }
  __syncthreads();
#pragma unroll
  for (int mi = 0; mi < 4; mi++)
#pragma unroll
    for (int r = 0; r < 4; r++)
      Ss[(mi << 4) + (lq << 2) + r][(w << 4) + lm] = f2bf(acc[mi][r]);
  __syncthreads();
  {
    int row = tid >> 2, seg = (tid & 3) << 4;
    if (i0 + row < 196) {
      unsigned short* dst = P + ((size_t)(bh * 10 + c) * 196 + i0 + row) * 64 + seg;
      *(uint4*)dst = *(uint4*)&Ss[row][seg];
      *(uint4*)(dst + 8) = *(uint4*)&Ss[row][seg + 8];
    }
  }
}

// ---- out1[bh][n][dd] = sum_c weights[bh,c] * P[bh][c][n][dd]  (bf16 out) ----
__global__ __launch_bounds__(256) void reduce_out1(const unsigned short* __restrict__ P,
                                                   const float* __restrict__ weights,
                                                   unsigned short* __restrict__ out1) {
  int t = blockIdx.x * 256 + threadIdx.x;
  int base = t << 2;
  int bh = base / 12544;
  int rem = base - bh * 12544;
  const float* wrow = weights + bh * 10;
  float a0 = 0.f, a1 = 0.f, a2 = 0.f, a3 = 0.f;
#pragma unroll
  for (int c = 0; c < 10; c++) {
    float wc = wrow[c];
    const unsigned short* p = P + ((size_t)(bh * 10 + c)) * 12544 + rem;
    ushort4 u = *(const ushort4*)p;
    a0 = fmaf(wc, bf2f(u.x), a0);
    a1 = fmaf(wc, bf2f(u.y), a1);
    a2 = fmaf(wc, bf2f(u.z), a2);
    a3 = fmaf(wc, bf2f(u.w), a3);
  }
  unsigned short s[4] = {f2bf(a0), f2bf(a1), f2bf(a2), f2bf(a3)};
  *(uint2*)&out1[base] = *(uint2*)s;
}

extern "C" void kernel_launch(void* const* d_in, const int* in_sizes, int n_in,
                              void* d_out, int out_size, void* d_ws, size_t ws_size,
                              hipStream_t stream) {
  (void)in_sizes; (void)n_in; (void)out_size; (void)ws_size;
  const float* x       = (const float*)d_in[0];
  const float* anchors = (const float*)d_in[1];
  const float* weights = (const float*)d_in[2];
  const float* Wqk     = (const float*)d_in[3];
  const float* Wqk2    = (const float*)d_in[4];
  const float* Wv      = (const float*)d_in[5];
  const float* Wproj   = (const float*)d_in[6];
  const float* bproj   = (const float*)d_in[7];
  char* ws = (char*)d_ws;                     // 53,174,272 bytes used
  float* out  = (float*)d_out;
  float* left = out + 802816;

  dim3 blk(256);
  pre_kernel<<<dim3(2020), blk, 0, stream>>>(x, anchors, Wqk, Wqk2, Wv, Wproj, ws);
  proj5<<<dim3(31, 8, 5), blk, 0, stream>>>(ws);
  rv_mfma<<<dim3(4, 640), blk, 0, stream>>>(ws);
  attn_mfma<<<dim3(4, 64, 10), blk, 0, stream>>>(ws, left, (unsigned short*)(ws + OFF_P));
  reduce_out1<<<dim3(784), blk, 0, stream>>>((const unsigned short*)(ws + OFF_P), weights,
                                             (unsigned short*)(ws + OFF_OUT1));
  final_gemm<<<dim3(25, 8), blk, 0, stream>>>((const unsigned short*)(ws + OFF_OUT1),
                                              (const unsigned short*)(ws + OFF_WPROJT), bproj, out);
}